// Round 1
// baseline (174.320 us; speedup 1.0000x reference)
//
#include <hip/hip_runtime.h>
#include <stdint.h>

#define N_DIM 4096
#define B_DIM 64

typedef __bf16 bf16x8 __attribute__((ext_vector_type(8)));
typedef float floatx4 __attribute__((ext_vector_type(4)));

union FragU { uint4 u; bf16x8 h; };

__device__ __forceinline__ unsigned short f2bf_rne(float f) {
    unsigned int u = __float_as_uint(f);
    u += 0x7fffu + ((u >> 16) & 1u);
    return (unsigned short)(u >> 16);
}

// c = Vmag*cos(ang), s = Vmag*sin(ang), packed bf16 in MFMA B-fragment order:
// idx = ((j>>3)*64 + b)*8 + (j&7)   (j = bus index / K, b = batch col)
__global__ __launch_bounds__(256) void pf_prep(
        const float* __restrict__ Vmag, const float* __restrict__ Vang,
        unsigned short* __restrict__ c_pk, unsigned short* __restrict__ s_pk) {
    int idx = blockIdx.x * 256 + threadIdx.x;   // = b*4096 + j
    int b = idx >> 12;
    int j = idx & 4095;
    float sv, cv;
    sincosf(Vang[idx], &sv, &cv);
    float v = Vmag[idx];
    int p = (((j >> 3) << 6) + b) * 8 + (j & 7);
    c_pk[p] = f2bf_rne(v * cv);
    s_pk[p] = f2bf_rne(v * sv);
}

// Block = 16 rows of G/B, 16 waves, 1 block/CU. NO LDS staging, NO main-loop
// barriers: each wave owns a private contiguous K-slice of 256 (8 steps of 32)
// and loads its MFMA A-fragments straight from global into registers (each
// 128B line fully consumed by one wave), 1-step register prefetch. G/B have
// zero cross-wave reuse so LDS staging only added vmcnt(0) drains at every
// __syncthreads with a single resident block. LDS = reduction buffer only.
// X = G*c + B*s ; Y = G*s - B*c (-c via sign-bit XOR).
__global__ __launch_bounds__(1024) void pf_gemm(
        const float* __restrict__ G, const float* __restrict__ Bm,
        const unsigned short* __restrict__ c_pk, const unsigned short* __restrict__ s_pk,
        const float* __restrict__ Vmag, const float* __restrict__ Vang,
        const float* __restrict__ P_in, const float* __restrict__ Q_in,
        float* __restrict__ out) {
    __shared__ __align__(16) float red[2 * 8 * 16 * 66];   // 67584 B
    const int tid = threadIdx.x;
    const int wave = tid >> 6;        // 0..15
    const int lane = tid & 63;
    const int n = lane & 15;          // A: row ; B/CD: col (batch)
    const int quad = lane >> 4;       // k-subgroup of 8
    const int i0 = blockIdx.x << 4;   // 16 rows per block

    // per-lane A-fragment pointers: row i0+n, k base = wave*256 + quad*8
    const float* gp = G  + (size_t)(i0 + n) * N_DIM + wave * 256 + quad * 8;
    const float* bp = Bm + (size_t)(i0 + n) * N_DIM + wave * 256 + quad * 8;
    // c/s fragment pointers: kgroup = wave*32 + t*4 + quad, col = t16*16 + n
    const unsigned short* cp = c_pk + ((size_t)(wave * 32 + quad) * 64 + n) * 8;
    const unsigned short* sp = s_pk + ((size_t)(wave * 32 + quad) * 64 + n) * 8;

    floatx4 accX[4], accY[4];
    #pragma unroll
    for (int t = 0; t < 4; ++t) {
        accX[t] = (floatx4){0.f, 0.f, 0.f, 0.f};
        accY[t] = (floatx4){0.f, 0.f, 0.f, 0.f};
    }

    // prefetch step 0
    float4 g0 = *(const float4*)(gp);
    float4 g1 = *(const float4*)(gp + 4);
    float4 h0 = *(const float4*)(bp);
    float4 h1 = *(const float4*)(bp + 4);

    #pragma unroll
    for (int t = 0; t < 8; ++t) {
        // prefetch step t+1 (register double-buffer; static after full unroll)
        float4 ng0, ng1, nh0, nh1;
        if (t < 7) {
            const float* g2 = gp + (t + 1) * 32;
            const float* b2 = bp + (t + 1) * 32;
            ng0 = *(const float4*)(g2);
            ng1 = *(const float4*)(g2 + 4);
            nh0 = *(const float4*)(b2);
            nh1 = *(const float4*)(b2 + 4);
        }

        // convert current A fragments fp32 -> bf16
        bf16x8 ag, ah;
        ag[0] = (__bf16)g0.x; ag[1] = (__bf16)g0.y; ag[2] = (__bf16)g0.z; ag[3] = (__bf16)g0.w;
        ag[4] = (__bf16)g1.x; ag[5] = (__bf16)g1.y; ag[6] = (__bf16)g1.z; ag[7] = (__bf16)g1.w;
        ah[0] = (__bf16)h0.x; ah[1] = (__bf16)h0.y; ah[2] = (__bf16)h0.z; ah[3] = (__bf16)h0.w;
        ah[4] = (__bf16)h1.x; ah[5] = (__bf16)h1.y; ah[6] = (__bf16)h1.z; ah[7] = (__bf16)h1.w;

        const unsigned short* cpt = cp + (size_t)t * 2048;
        const unsigned short* spt = sp + (size_t)t * 2048;

        // c-phase: X += G*c ; Y += B*(-c)
        uint4 cu[4];
        #pragma unroll
        for (int t16 = 0; t16 < 4; ++t16) cu[t16] = *(const uint4*)(cpt + t16 * 128);
        #pragma unroll
        for (int t16 = 0; t16 < 4; ++t16) {
            FragU cf, nf;
            cf.u = cu[t16];
            nf.u.x = cu[t16].x ^ 0x80008000u;
            nf.u.y = cu[t16].y ^ 0x80008000u;
            nf.u.z = cu[t16].z ^ 0x80008000u;
            nf.u.w = cu[t16].w ^ 0x80008000u;
            accX[t16] = __builtin_amdgcn_mfma_f32_16x16x32_bf16(ag, cf.h, accX[t16], 0, 0, 0);
            accY[t16] = __builtin_amdgcn_mfma_f32_16x16x32_bf16(ah, nf.h, accY[t16], 0, 0, 0);
        }

        // s-phase: X += B*s ; Y += G*s
        uint4 su[4];
        #pragma unroll
        for (int t16 = 0; t16 < 4; ++t16) su[t16] = *(const uint4*)(spt + t16 * 128);
        #pragma unroll
        for (int t16 = 0; t16 < 4; ++t16) {
            FragU sf;
            sf.u = su[t16];
            accX[t16] = __builtin_amdgcn_mfma_f32_16x16x32_bf16(ah, sf.h, accX[t16], 0, 0, 0);
            accY[t16] = __builtin_amdgcn_mfma_f32_16x16x32_bf16(ag, sf.h, accY[t16], 0, 0, 0);
        }

        g0 = ng0; g1 = ng1; h0 = nh0; h1 = nh1;
    }

    // cross-wave reduction. C/D layout: col(b)=lane&15, row(m)=quad*4+reg
    #define RED(x, wp, m, b) red[(((x) * 8 + (wp)) * 16 + (m)) * 66 + (b)]
    if (wave >= 8) {
        #pragma unroll
        for (int t = 0; t < 4; ++t)
            #pragma unroll
            for (int r = 0; r < 4; ++r) {
                RED(0, wave - 8, (quad << 2) + r, (t << 4) + n) = accX[t][r];
                RED(1, wave - 8, (quad << 2) + r, (t << 4) + n) = accY[t][r];
            }
    }
    __syncthreads();
    if (wave < 8) {
        #pragma unroll
        for (int t = 0; t < 4; ++t)
            #pragma unroll
            for (int r = 0; r < 4; ++r) {
                RED(0, wave, (quad << 2) + r, (t << 4) + n) += accX[t][r];
                RED(1, wave, (quad << 2) + r, (t << 4) + n) += accY[t][r];
            }
    }
    __syncthreads();

    // 1024 outputs (m,b); 1024 threads -> 1 each; fused epilogue.
    // c,s recomputed from Vmag/Vang (bitwise-identical to prep's fp32 math).
    {
        int bb = tid >> 4;
        int m = tid & 15;
        float X = 0.f, Y = 0.f;
        #pragma unroll
        for (int w = 0; w < 8; ++w) {
            X += RED(0, w, m, bb);
            Y += RED(1, w, m, bb);
        }
        size_t off = (size_t)bb * N_DIM + i0 + m;
        float sv, cv;
        sincosf(Vang[off], &sv, &cv);
        float v = Vmag[off];
        float c = v * cv;
        float s = v * sv;
        out[off] = c * X + s * Y - P_in[off];                          // res_P
        out[(size_t)B_DIM * N_DIM + off] = s * X - c * Y - Q_in[off];  // res_Q
    }
}

extern "C" void kernel_launch(void* const* d_in, const int* in_sizes, int n_in,
                              void* d_out, int out_size, void* d_ws, size_t ws_size,
                              hipStream_t stream) {
    const float* Vmag = (const float*)d_in[0];
    const float* Vang = (const float*)d_in[1];
    const float* P_in = (const float*)d_in[2];
    const float* Q_in = (const float*)d_in[3];
    const float* G    = (const float*)d_in[4];
    const float* Bm   = (const float*)d_in[5];
    float* out = (float*)d_out;

    char* ws = (char*)d_ws;
    unsigned short* c_pk = (unsigned short*)(ws);                    // 512 KB
    unsigned short* s_pk = (unsigned short*)(ws + (512u << 10));     // 512 KB

    hipLaunchKernelGGL(pf_prep, dim3((B_DIM * N_DIM) / 256), dim3(256), 0, stream,
                       Vmag, Vang, c_pk, s_pk);
    hipLaunchKernelGGL(pf_gemm, dim3(N_DIM / 16), dim3(1024), 0, stream,
                       G, Bm, c_pk, s_pk, Vmag, Vang, P_in, Q_in, out);
}